// Round 12
// baseline (75.271 us; speedup 1.0000x reference)
//
#include <hip/hip_runtime.h>
#include <hip/hip_bf16.h>
#include <stdint.h>

// ---------- helpers ----------
typedef __attribute__((ext_vector_type(8))) __bf16 bf16x8;
typedef __attribute__((ext_vector_type(8))) unsigned short u16x8;
typedef __attribute__((ext_vector_type(4))) float f32x4;

__device__ inline float bf2f(unsigned short u) {
  union { unsigned u; float f; } z; z.u = ((unsigned)u) << 16; return z.f;
}
__device__ inline unsigned short f2bf(float f) {
  union { float f; unsigned u; } z; z.f = f;
  unsigned r = z.u + 0x7fffu + ((z.u >> 16) & 1u);
  return (unsigned short)(r >> 16);
}
__device__ inline void gload_lds16(const void* g, void* l) {
  __builtin_amdgcn_global_load_lds((const __attribute__((address_space(1))) void*)g,
                                   (__attribute__((address_space(3))) void*)l, 16, 0, 0);
}
__device__ inline float fp8tof(unsigned u) {
  return __builtin_amdgcn_cvt_f32_fp8((int)u, 0);
}

// ---------- fused q/k/v projection + weight conversions ----------
// grid (128, 7): by 0-1 -> q bf16 (A=x); 2-3 -> K fp8; 4-5 -> V fp8 (A=mem); 6 -> convert W's.
__global__ __launch_bounds__(256, 2) void gemm_proj(
    const float* __restrict__ x, const float* __restrict__ mem,
    const float* __restrict__ Wq, const float* __restrict__ Wk, const float* __restrict__ Wv,
    const float* __restrict__ Wo, const float* __restrict__ We, const float* __restrict__ Ws,
    const float* __restrict__ Wrpe, const float* __restrict__ brpe,
    const float* __restrict__ bq, const float* __restrict__ bk, const float* __restrict__ bv,
    unsigned short* __restrict__ qbuf, unsigned char* __restrict__ kf8,
    unsigned char* __restrict__ vf8,
    unsigned short* __restrict__ wob, unsigned short* __restrict__ web,
    unsigned short* __restrict__ wsb, float4* __restrict__ rpe4) {
  const int tid = threadIdx.x;
  const int by = blockIdx.y;
  const long bm = blockIdx.x;

  if (by == 6) {
#pragma unroll
    for (int it = 0; it < 3; ++it) {
      const int j = (int)bm + 128 * it;
      if (j < 64) {
        const float4 v = *(const float4*)(Wo + (long)j * 1024 + tid * 4);
        ushort4 o; o.x = f2bf(v.x); o.y = f2bf(v.y); o.z = f2bf(v.z); o.w = f2bf(v.w);
        *(ushort4*)(wob + (long)j * 1024 + tid * 4) = o;
      } else if (j < 192) {
        const float4 v = *(const float4*)(We + (long)(j - 64) * 1024 + tid * 4);
        ushort4 o; o.x = f2bf(v.x); o.y = f2bf(v.y); o.z = f2bf(v.z); o.w = f2bf(v.w);
        *(ushort4*)(web + (long)(j - 64) * 1024 + tid * 4) = o;
      } else if (j < 320) {
        const float4 v = *(const float4*)(Ws + (long)(j - 192) * 1024 + tid * 4);
        ushort4 o; o.x = f2bf(v.x); o.y = f2bf(v.y); o.z = f2bf(v.z); o.w = f2bf(v.w);
        *(ushort4*)(wsb + (long)(j - 192) * 1024 + tid * 4) = o;
      } else if (j == 320) {
        if (tid < 128) {
          float4 r;
          r.x = Wrpe[3 * tid]; r.y = Wrpe[3 * tid + 1]; r.z = Wrpe[3 * tid + 2]; r.w = brpe[tid];
          rpe4[tid] = r;
        }
      }
    }
    return;
  }

  __shared__ __attribute__((aligned(16))) char lds[4096 + 8192];  // A 4KB | B 8KB (bf16)
  const int lane = tid & 63;
  const int wm = tid >> 7, wo = (tid >> 6) & 1;

  const float* Ab; const float* Wf; const float* biasp;
  if (by < 2)      { Ab = x;   Wf = Wq + (long)by * 128 * 256;       biasp = bq + by * 128; }
  else if (by < 4) { Ab = mem; Wf = Wk + (long)(by - 2) * 128 * 256; biasp = bk + (by - 2) * 128; }
  else             { Ab = mem; Wf = Wv + (long)(by - 4) * 128 * 256; biasp = bv + (by - 4) * 128; }

  f32x4 acc[2][4] = {};
  for (int kt = 0; kt < 8; ++kt) {
#pragma unroll
    for (int c = 0; c < 2; ++c) {
      const int fb = c * 4096 + tid * 16;
      const int row = fb >> 7, colb = fb & 127;
      const float4 a4 = *(const float4*)((const char*)Ab + (bm * 64 + row) * 1024 + kt * 128 + colb);
      ushort4 o; o.x = f2bf(a4.x); o.y = f2bf(a4.y); o.z = f2bf(a4.z); o.w = f2bf(a4.w);
      *(ushort4*)(lds + row * 64 + (colb >> 1)) = o;
    }
#pragma unroll
    for (int c = 0; c < 4; ++c) {
      const int fb = c * 4096 + tid * 16;
      const int row = fb >> 7, colb = fb & 127;
      const float4 a4 = *(const float4*)((const char*)Wf + (long)row * 1024 + kt * 128 + colb);
      ushort4 o; o.x = f2bf(a4.x); o.y = f2bf(a4.y); o.z = f2bf(a4.z); o.w = f2bf(a4.w);
      *(ushort4*)(lds + 4096 + row * 64 + (colb >> 1)) = o;
    }
    __syncthreads();
    bf16x8 af[2], bfr[4];
    const int kb = (lane >> 4) * 16;
#pragma unroll
    for (int i = 0; i < 2; ++i)
      af[i] = *(const bf16x8*)(lds + (wm * 32 + i * 16 + (lane & 15)) * 64 + kb);
#pragma unroll
    for (int j = 0; j < 4; ++j)
      bfr[j] = *(const bf16x8*)(lds + 4096 + (wo * 64 + j * 16 + (lane & 15)) * 64 + kb);
#pragma unroll
    for (int i = 0; i < 2; ++i)
#pragma unroll
      for (int j = 0; j < 4; ++j)
        acc[i][j] = __builtin_amdgcn_mfma_f32_16x16x32_bf16(af[i], bfr[j], acc[i][j], 0, 0, 0);
    __syncthreads();
  }

  if (by < 2) {
    // q: bf16 out
#pragma unroll
    for (int i = 0; i < 2; ++i) {
#pragma unroll
      for (int j = 0; j < 4; ++j) {
        const int lc = wo * 64 + j * 16 + (lane & 15);
        const float bvv = biasp[lc];
#pragma unroll
        for (int r = 0; r < 4; ++r) {
          const long rowg = bm * 64 + wm * 32 + i * 16 + (lane >> 4) * 4 + r;
          qbuf[rowg * 256 + by * 128 + lc] = f2bf(acc[i][j][r] + bvv);
        }
      }
    }
  } else {
    // K/V: fp8 e4m3 out, lane-pair packed ushort stores (even lanes)
    unsigned char* of8 = (by < 4) ? kf8 : vf8;
    const int cb = (by & 1) * 128;
#pragma unroll
    for (int i = 0; i < 2; ++i) {
#pragma unroll
      for (int j = 0; j < 4; ++j) {
        const int lc = wo * 64 + j * 16 + (lane & 15);
        const float bvv = biasp[lc];
#pragma unroll
        for (int r = 0; r < 4; ++r) {
          const long rowg = bm * 64 + wm * 32 + i * 16 + (lane >> 4) * 4 + r;
          const float v = acc[i][j][r] + bvv;
          const float vo = __shfl_xor(v, 1, 64);  // partner holds col+1 (even lane view)
          if (!(lane & 1)) {
            const int pk = __builtin_amdgcn_cvt_pk_fp8_f32(v, vo, 0, false);
            *(unsigned short*)(of8 + rowg * 256 + cb + lc) = (unsigned short)pk;
          }
        }
      }
    }
  }
}

// ---------- fused gather + RPE rotary + MHA; fp8 K/V, poly trig ----------
__global__ __launch_bounds__(256, 6) void attn4(
    const unsigned short* __restrict__ qb,   // N x 256 (bf16)
    const unsigned char* __restrict__ kf8,   // M x 256 (fp8 e4m3)
    const unsigned char* __restrict__ vf8,   // M x 256 (fp8 e4m3)
    const int* __restrict__ idx,             // N x 32
    const float* __restrict__ icoord,        // N x 3
    const float* __restrict__ mcoord,        // M x 3
    const float* __restrict__ mask,          // N x 32
    const float4* __restrict__ rpe4,         // 128 x {w0,w1,w2,b}
    unsigned short* __restrict__ hb)         // N x 256 (bf16)
{
  __shared__ int idx_s[32];
  __shared__ float4 relm_s[32];
  __shared__ float4 rpe_s[128];
  __shared__ float p_s[256];
  __shared__ __attribute__((aligned(16))) unsigned char vls[32][256];

  const int n = blockIdx.x, t = threadIdx.x;
  if (t < 128) rpe_s[t] = rpe4[t];
  if (t < 32) {
    const int m = idx[n * 32 + t];
    idx_s[t] = m;
    float4 rm;
    rm.x = mcoord[(long)m * 3 + 0] - icoord[(long)n * 3 + 0];
    rm.y = mcoord[(long)m * 3 + 1] - icoord[(long)n * 3 + 1];
    rm.z = mcoord[(long)m * 3 + 2] - icoord[(long)n * 3 + 2];
    rm.w = mask[n * 32 + t];
    relm_s[t] = rm;
  }
  __syncthreads();

  // stage V fp8 (8KB) via global_load_lds, overlapped with score phase
#pragma unroll
  for (int i = 0; i < 2; ++i) {
    const int b = i * 4096 + t * 16;
    const int r = b >> 8, cb = b & 255;
    gload_lds16(vf8 + (long)idx_s[r] * 256 + cb, (char*)vls + b);
  }

  const int h = t >> 5, k = t & 31;
  const float4 rm = relm_s[k];
  const long krow = idx_s[k];

  uint4 kw[2];   // 32 fp8 bytes of K for this (k, head)
  {
    const uint4* kp = (const uint4*)(kf8 + krow * 256 + h * 32);
    kw[0] = kp[0]; kw[1] = kp[1];
  }
  u16x8 qv8[4];
  {
    const u16x8* qp = (const u16x8*)(qb + (long)n * 256 + h * 32);
#pragma unroll
    for (int i = 0; i < 4; ++i) qv8[i] = qp[i];
  }

  float sc = 0.f;
#pragma unroll
  for (int j2 = 0; j2 < 16; ++j2) {
    const float4 wj = rpe_s[h * 16 + j2];
    const float ang = fmaf(wj.x, rm.x, fmaf(wj.y, rm.y, fmaf(wj.z, rm.z, wj.w)));
    const float x2 = ang * ang;                       // |ang| small: Taylor ok
    const float sn = ang * fmaf(x2, -0.16666667f, 1.f);
    const float cs = fmaf(x2, fmaf(x2, 0.041666667f, -0.5f), 1.f);
    // K elements 2*j2 (byte b0) and 2*j2+1: decode via shift + cvt_f32_fp8(.,0)
    const unsigned dw = ((const unsigned*)kw)[j2 >> 1];
    const unsigned sh = (j2 & 1) * 16;
    const float x0 = fp8tof((dw >> sh) & 0xffu);
    const float x1 = fp8tof((dw >> (sh + 8)) & 0xffu);
    const int wi = j2 >> 2, e0 = (j2 & 3) * 2;
    const float q0 = bf2f(qv8[wi][e0]), q1 = bf2f(qv8[wi][e0 + 1]);
    const float k0 = fmaf(x0, cs, -x1 * sn);
    const float k1 = fmaf(x0, sn, x1 * cs);
    sc = fmaf(q0, k0, sc);
    sc = fmaf(q1, k1, sc);
  }
  sc = sc * 0.17677669529663687f - 1e6f * (1.f - rm.w);

  float mx = sc;
#pragma unroll
  for (int m = 16; m > 0; m >>= 1) mx = fmaxf(mx, __shfl_xor(mx, m, 32));
  const float e = __expf(sc - mx);
  float sum = e;
#pragma unroll
  for (int m = 16; m > 0; m >>= 1) sum += __shfl_xor(sum, m, 32);
  p_s[t] = e / sum;
  __syncthreads();  // V staged + p_s visible

  float acc = 0.f;
#pragma unroll
  for (int k4 = 0; k4 < 8; ++k4) {
    const float4 p4 = *(const float4*)(p_s + (t >> 5) * 32 + k4 * 4);
    acc = fmaf(p4.x, fp8tof(vls[k4 * 4 + 0][t]), acc);
    acc = fmaf(p4.y, fp8tof(vls[k4 * 4 + 1][t]), acc);
    acc = fmaf(p4.z, fp8tof(vls[k4 * 4 + 2][t]), acc);
    acc = fmaf(p4.w, fp8tof(vls[k4 * 4 + 3][t]), acc);
  }
  hb[(long)n * 256 + t] = f2bf(acc);
}

// ---------- bf16 GEMM + relu + bf16 out (FFN1). BM=64, BN=128 ----------
__global__ __launch_bounds__(256, 2) void gemm_relu(
    const unsigned short* __restrict__ A,   // M x 256
    const unsigned short* __restrict__ W,   // 512 x 256
    const float* __restrict__ bias,         // 512
    unsigned short* __restrict__ outb) {    // M x 512
  __shared__ __attribute__((aligned(16))) char lds[(64 + 128) * 64];
  const int tid = threadIdx.x, lane = tid & 63;
  const int wm = tid >> 7, wo = (tid >> 6) & 1;
  const long bm = blockIdx.x, bo = blockIdx.y;

  f32x4 acc[2][4] = {};
  const char* Ab = (const char*)(A + bm * 64 * 256);
  const char* Wb = (const char*)(W + bo * 128 * 256);
  for (int kt = 0; kt < 8; ++kt) {
    {
      const int fb = tid * 16;
      gload_lds16(Ab + (long)(fb >> 6) * 512 + kt * 64 + (fb & 63), lds + fb);
    }
#pragma unroll
    for (int c = 0; c < 2; ++c) {
      const int fb = c * 4096 + tid * 16;
      gload_lds16(Wb + (long)(fb >> 6) * 512 + kt * 64 + (fb & 63), lds + 4096 + fb);
    }
    __syncthreads();
    bf16x8 af[2], bfr[4];
    const int kb = (lane >> 4) * 16;
#pragma unroll
    for (int i = 0; i < 2; ++i)
      af[i] = *(const bf16x8*)(lds + (wm * 32 + i * 16 + (lane & 15)) * 64 + kb);
#pragma unroll
    for (int j = 0; j < 4; ++j)
      bfr[j] = *(const bf16x8*)(lds + 4096 + (wo * 64 + j * 16 + (lane & 15)) * 64 + kb);
#pragma unroll
    for (int i = 0; i < 2; ++i)
#pragma unroll
      for (int j = 0; j < 4; ++j)
        acc[i][j] = __builtin_amdgcn_mfma_f32_16x16x32_bf16(af[i], bfr[j], acc[i][j], 0, 0, 0);
    __syncthreads();
  }
#pragma unroll
  for (int i = 0; i < 2; ++i) {
#pragma unroll
    for (int j = 0; j < 4; ++j) {
      const int colg = (int)bo * 128 + wo * 64 + j * 16 + (lane & 15);
      const float bvv = bias[colg];
#pragma unroll
      for (int r = 0; r < 4; ++r) {
        const long rowg = bm * 64 + wm * 32 + i * 16 + (lane >> 4) * 4 + r;
        const float v = acc[i][j][r] + bvv;
        outb[rowg * 512 + colg] = f2bf(v > 0.f ? v : 0.f);
      }
    }
  }
}

// ---------- GEMM + bias + residual + LayerNorm fused epilogue ----------
// BM=16, BN=256 (full row per block), grid (M/16). KT = K/32.
template <int KT, int OUT_BF16, int RES_BF16>
__global__ __launch_bounds__(256, 2) void gemm_ln(
    const unsigned short* __restrict__ A,   // M x K bf16
    const unsigned short* __restrict__ W,   // 256 x K bf16
    const float* __restrict__ bias,         // 256
    const float* __restrict__ resf,         // M x 256 f32 (RES_BF16=0)
    const unsigned short* __restrict__ resb,// M x 256 bf16 (RES_BF16=1)
    const float* __restrict__ g, const float* __restrict__ b,
    float* __restrict__ outf,
    unsigned short* __restrict__ outb) {
  __shared__ __attribute__((aligned(16))) char lds[1024 + 16384];  // A 1KB | B 16KB
  __shared__ float2 part[4][16];
  const int tid = threadIdx.x, lane = tid & 63;
  const int wo = tid >> 6;
  const long bm = blockIdx.x;
  constexpr int K = KT * 32;

  f32x4 acc[4] = {};
  const char* Ab = (const char*)(A + bm * 16 * (long)K);
  for (int kt = 0; kt < KT; ++kt) {
    if (tid < 64) {
      const int fb = tid * 16;
      gload_lds16(Ab + (long)(fb >> 6) * (K * 2) + kt * 64 + (fb & 63), lds + fb);
    }
#pragma unroll
    for (int c = 0; c < 4; ++c) {
      const int fb = c * 4096 + tid * 16;
      gload_lds16((const char*)W + (long)(fb >> 6) * (K * 2) + kt * 64 + (fb & 63), lds + 1024 + fb);
    }
    __syncthreads();
    bf16x8 af, bfr[4];
    const int kb = (lane >> 4) * 16;
    af = *(const bf16x8*)(lds + ((lane & 15)) * 64 + kb);
#pragma unroll
    for (int j = 0; j < 4; ++j)
      bfr[j] = *(const bf16x8*)(lds + 1024 + (wo * 64 + j * 16 + (lane & 15)) * 64 + kb);
#pragma unroll
    for (int j = 0; j < 4; ++j)
      acc[j] = __builtin_amdgcn_mfma_f32_16x16x32_bf16(af, bfr[j], acc[j], 0, 0, 0);
    __syncthreads();
  }

  float gj[4], bj[4], biasj[4];
  int colg[4];
#pragma unroll
  for (int j = 0; j < 4; ++j) {
    colg[j] = wo * 64 + j * 16 + (lane & 15);
    gj[j] = g[colg[j]]; bj[j] = b[colg[j]]; biasj[j] = bias[colg[j]];
  }
  float v[4][4];
#pragma unroll
  for (int r = 0; r < 4; ++r) {
    const int row_local = (lane >> 4) * 4 + r;
    const long rowg = bm * 16 + row_local;
    float s = 0.f, s2 = 0.f;
#pragma unroll
    for (int j = 0; j < 4; ++j) {
      const float rv = RES_BF16 ? bf2f(resb[rowg * 256 + colg[j]]) : resf[rowg * 256 + colg[j]];
      float vv = acc[j][r] + biasj[j] + rv;
      v[j][r] = vv;
      s += vv; s2 = fmaf(vv, vv, s2);
    }
#pragma unroll
    for (int m = 8; m > 0; m >>= 1) { s += __shfl_xor(s, m, 16); s2 += __shfl_xor(s2, m, 16); }
    if ((lane & 15) == 0) part[wo][row_local] = make_float2(s, s2);
  }
  __syncthreads();
#pragma unroll
  for (int r = 0; r < 4; ++r) {
    const int row_local = (lane >> 4) * 4 + r;
    const long rowg = bm * 16 + row_local;
    float s = 0.f, s2 = 0.f;
#pragma unroll
    for (int wq = 0; wq < 4; ++wq) { s += part[wq][row_local].x; s2 += part[wq][row_local].y; }
    const float mu = s * (1.f / 256.f);
    const float var = s2 * (1.f / 256.f) - mu * mu;
    const float inv = rsqrtf(var + 1e-5f);
#pragma unroll
    for (int j = 0; j < 4; ++j) {
      const float y = (v[j][r] - mu) * inv * gj[j] + bj[j];
      if (OUT_BF16) outb[rowg * 256 + colg[j]] = f2bf(y);
      else outf[rowg * 256 + colg[j]] = y;
    }
  }
}

// ---------- launch ----------
extern "C" void kernel_launch(void* const* d_in, const int* in_sizes, int n_in,
                              void* d_out, int out_size, void* d_ws, size_t ws_size,
                              hipStream_t stream) {
  const float* x    = (const float*)d_in[0];
  const float* mem  = (const float*)d_in[1];
  const int* idx    = (const int*)d_in[2];
  const float* ic   = (const float*)d_in[3];
  const float* mc   = (const float*)d_in[4];
  const float* mask = (const float*)d_in[5];
  const float* Wq = (const float*)d_in[6];  const float* bq = (const float*)d_in[7];
  const float* Wk = (const float*)d_in[8];  const float* bk = (const float*)d_in[9];
  const float* Wv = (const float*)d_in[10]; const float* bv = (const float*)d_in[11];
  const float* Wo = (const float*)d_in[12]; const float* bo = (const float*)d_in[13];
  const float* g1 = (const float*)d_in[14]; const float* b1 = (const float*)d_in[15];
  const float* Wrpe = (const float*)d_in[16]; const float* brpe = (const float*)d_in[17];
  const float* We = (const float*)d_in[18]; const float* be = (const float*)d_in[19];
  const float* Ws = (const float*)d_in[20]; const float* bs = (const float*)d_in[21];
  const float* g2 = (const float*)d_in[22]; const float* b2 = (const float*)d_in[23];

  char* w = (char*)d_ws;
  const size_t MB = 1ull << 20;
  unsigned char*  kf8   = (unsigned char*)(w + 0);         // 2MB (M x 256 fp8)
  unsigned char*  vf8   = (unsigned char*)(w + 2 * MB);    // 2MB
  unsigned short* qbuf  = (unsigned short*)(w + 4 * MB);   // 4MB
  unsigned short* hb    = (unsigned short*)(w + 8 * MB);   // 4MB
  unsigned short* out1b = (unsigned short*)(w + 12 * MB);  // 4MB
  unsigned short* ffb   = (unsigned short*)(w + 16 * MB);  // 8MB (8192x512 bf16)
  unsigned short* wob  = (unsigned short*)(w + 24 * MB);   // 128KB
  unsigned short* web  = wob + 65536;                      // 256KB
  unsigned short* wsb  = web + 131072;                     // 256KB
  float4*         rpe4 = (float4*)(wsb + 131072);          // 2KB

  // fused q/k/v projections + weight conversions (one launch)
  gemm_proj<<<dim3(128, 7), 256, 0, stream>>>(
      x, mem, Wq, Wk, Wv, Wo, We, Ws, Wrpe, brpe, bq, bk, bv,
      qbuf, kf8, vf8, wob, web, wsb, rpe4);

  // fused gather + rotary + attention (fp8 K/V)
  attn4<<<8192, 256, 0, stream>>>(qbuf, kf8, vf8, idx, ic, mc, mask, rpe4, hb);

  // output proj + residual(x, f32) + LN1 -> bf16
  gemm_ln<8, 1, 0><<<512, 256, 0, stream>>>(
      hb, wob, bo, x, nullptr, g1, b1, nullptr, out1b);

  // FFN1 (relu)
  gemm_relu<<<dim3(128, 4), 256, 0, stream>>>(out1b, web, be, ffb);

  // FFN2 + residual(out1b, bf16) + LN2 -> d_out (f32)
  gemm_ln<16, 0, 1><<<512, 256, 0, stream>>>(
      ffb, wsb, bs, nullptr, out1b, g2, b2, (float*)d_out, nullptr);
}

// Round 13
// 73.820 us; speedup vs baseline: 1.0197x; 1.0197x over previous
//
#include <hip/hip_runtime.h>
#include <hip/hip_bf16.h>
#include <stdint.h>

// ---------- helpers ----------
typedef __attribute__((ext_vector_type(8))) __bf16 bf16x8;
typedef __attribute__((ext_vector_type(8))) unsigned short u16x8;
typedef __attribute__((ext_vector_type(4))) float f32x4;

__device__ inline float bf2f(unsigned short u) {
  union { unsigned u; float f; } z; z.u = ((unsigned)u) << 16; return z.f;
}
__device__ inline unsigned short f2bf(float f) {
  union { float f; unsigned u; } z; z.f = f;
  unsigned r = z.u + 0x7fffu + ((z.u >> 16) & 1u);
  return (unsigned short)(r >> 16);
}
__device__ inline void gload_lds16(const void* g, void* l) {
  __builtin_amdgcn_global_load_lds((const __attribute__((address_space(1))) void*)g,
                                   (__attribute__((address_space(3))) void*)l, 16, 0, 0);
}
__device__ inline float fp8tof(unsigned u) {
  return __builtin_amdgcn_cvt_f32_fp8((int)u, 0);
}
// |a| < ~0.4: Taylor sin/cos, error < 2e-5 (proven in R8)
__device__ inline void tsincos(float a, float& sn, float& cs) {
  const float x2 = a * a;
  sn = a * fmaf(x2, -0.16666667f, 1.f);
  cs = fmaf(x2, fmaf(x2, 0.041666667f, -0.5f), 1.f);
}

// ---------- fused q/k/v projection + absolute-RoPE epilogue + weight conversions ----------
// grid (128, 7): by 0-1 -> q bf16, rotated by beta=w·ic (A=x); 2-3 -> K fp8 rotated by
// alpha=w·mc+b; 4-5 -> V fp8 (A=mem); 6 -> convert Wo/We/Ws.
// Identity: q^T R(alpha-beta) k == (R(beta)q)^T (R(alpha)k)  -> attn needs no trig.
__global__ __launch_bounds__(256, 2) void gemm_proj(
    const float* __restrict__ x, const float* __restrict__ mem,
    const float* __restrict__ Wq, const float* __restrict__ Wk, const float* __restrict__ Wv,
    const float* __restrict__ Wo, const float* __restrict__ We, const float* __restrict__ Ws,
    const float* __restrict__ Wrpe, const float* __restrict__ brpe,
    const float* __restrict__ bq, const float* __restrict__ bk, const float* __restrict__ bv,
    const float* __restrict__ icoord, const float* __restrict__ mcoord,
    unsigned short* __restrict__ qbuf, unsigned char* __restrict__ kf8,
    unsigned char* __restrict__ vf8,
    unsigned short* __restrict__ wob, unsigned short* __restrict__ web,
    unsigned short* __restrict__ wsb) {
  const int tid = threadIdx.x;
  const int by = blockIdx.y;
  const long bm = blockIdx.x;

  if (by == 6) {
#pragma unroll
    for (int it = 0; it < 3; ++it) {
      const int j = (int)bm + 128 * it;
      if (j < 64) {
        const float4 v = *(const float4*)(Wo + (long)j * 1024 + tid * 4);
        ushort4 o; o.x = f2bf(v.x); o.y = f2bf(v.y); o.z = f2bf(v.z); o.w = f2bf(v.w);
        *(ushort4*)(wob + (long)j * 1024 + tid * 4) = o;
      } else if (j < 192) {
        const float4 v = *(const float4*)(We + (long)(j - 64) * 1024 + tid * 4);
        ushort4 o; o.x = f2bf(v.x); o.y = f2bf(v.y); o.z = f2bf(v.z); o.w = f2bf(v.w);
        *(ushort4*)(web + (long)(j - 64) * 1024 + tid * 4) = o;
      } else if (j < 320) {
        const float4 v = *(const float4*)(Ws + (long)(j - 192) * 1024 + tid * 4);
        ushort4 o; o.x = f2bf(v.x); o.y = f2bf(v.y); o.z = f2bf(v.z); o.w = f2bf(v.w);
        *(ushort4*)(wsb + (long)(j - 192) * 1024 + tid * 4) = o;
      }
    }
    return;
  }

  __shared__ __attribute__((aligned(16))) char lds[4096 + 8192];  // A 4KB | B 8KB (bf16)
  __shared__ float4 rpe_l[128];                                    // {w0,w1,w2,b} per pair
  const int lane = tid & 63;
  const int wm = tid >> 7, wo = (tid >> 6) & 1;

  if (tid < 128)
    rpe_l[tid] = make_float4(Wrpe[3 * tid], Wrpe[3 * tid + 1], Wrpe[3 * tid + 2], brpe[tid]);

  const float* Ab; const float* Wf; const float* biasp;
  if (by < 2)      { Ab = x;   Wf = Wq + (long)by * 128 * 256;       biasp = bq + by * 128; }
  else if (by < 4) { Ab = mem; Wf = Wk + (long)(by - 2) * 128 * 256; biasp = bk + (by - 2) * 128; }
  else             { Ab = mem; Wf = Wv + (long)(by - 4) * 128 * 256; biasp = bv + (by - 4) * 128; }

  f32x4 acc[2][4] = {};
  for (int kt = 0; kt < 8; ++kt) {
#pragma unroll
    for (int c = 0; c < 2; ++c) {
      const int fb = c * 4096 + tid * 16;
      const int row = fb >> 7, colb = fb & 127;
      const float4 a4 = *(const float4*)((const char*)Ab + (bm * 64 + row) * 1024 + kt * 128 + colb);
      ushort4 o; o.x = f2bf(a4.x); o.y = f2bf(a4.y); o.z = f2bf(a4.z); o.w = f2bf(a4.w);
      *(ushort4*)(lds + row * 64 + (colb >> 1)) = o;
    }
#pragma unroll
    for (int c = 0; c < 4; ++c) {
      const int fb = c * 4096 + tid * 16;
      const int row = fb >> 7, colb = fb & 127;
      const float4 a4 = *(const float4*)((const char*)Wf + (long)row * 1024 + kt * 128 + colb);
      ushort4 o; o.x = f2bf(a4.x); o.y = f2bf(a4.y); o.z = f2bf(a4.z); o.w = f2bf(a4.w);
      *(ushort4*)(lds + 4096 + row * 64 + (colb >> 1)) = o;
    }
    __syncthreads();
    bf16x8 af[2], bfr[4];
    const int kb = (lane >> 4) * 16;
#pragma unroll
    for (int i = 0; i < 2; ++i)
      af[i] = *(const bf16x8*)(lds + (wm * 32 + i * 16 + (lane & 15)) * 64 + kb);
#pragma unroll
    for (int j = 0; j < 4; ++j)
      bfr[j] = *(const bf16x8*)(lds + 4096 + (wo * 64 + j * 16 + (lane & 15)) * 64 + kb);
#pragma unroll
    for (int i = 0; i < 2; ++i)
#pragma unroll
      for (int j = 0; j < 4; ++j)
        acc[i][j] = __builtin_amdgcn_mfma_f32_16x16x32_bf16(af[i], bfr[j], acc[i][j], 0, 0, 0);
    __syncthreads();
  }

  if (by < 2) {
    // q: rotate by beta = w·ic[n] (no bias term), bf16 out
#pragma unroll
    for (int i = 0; i < 2; ++i) {
#pragma unroll
      for (int r = 0; r < 4; ++r) {
        const long rowg = bm * 64 + wm * 32 + i * 16 + (lane >> 4) * 4 + r;
        const float c0 = icoord[rowg * 3], c1 = icoord[rowg * 3 + 1], c2 = icoord[rowg * 3 + 2];
#pragma unroll
        for (int j = 0; j < 4; ++j) {
          const int lc = wo * 64 + j * 16 + (lane & 15);
          const float v = acc[i][j][r] + biasp[lc];
          const float vo = __shfl_xor(v, 1, 64);
          const float4 wj = rpe_l[(by * 128 + lc) >> 1];
          const float ang = fmaf(wj.x, c0, fmaf(wj.y, c1, wj.z * c2));
          float sn, cs; tsincos(ang, sn, cs);
          // even lane holds x0 -> x0*cs - x1*sn; odd holds x1 -> x0*sn + x1*cs
          const float res = (lane & 1) ? fmaf(vo, sn, v * cs) : fmaf(v, cs, -(vo * sn));
          qbuf[rowg * 256 + by * 128 + lc] = f2bf(res);
        }
      }
    }
  } else {
    const bool isK = (by < 4);
    unsigned char* of8 = isK ? kf8 : vf8;
    const int cb = (by & 1) * 128;
#pragma unroll
    for (int i = 0; i < 2; ++i) {
#pragma unroll
      for (int r = 0; r < 4; ++r) {
        const long rowg = bm * 64 + wm * 32 + i * 16 + (lane >> 4) * 4 + r;
        float c0 = 0.f, c1 = 0.f, c2 = 0.f;
        if (isK) { c0 = mcoord[rowg * 3]; c1 = mcoord[rowg * 3 + 1]; c2 = mcoord[rowg * 3 + 2]; }
#pragma unroll
        for (int j = 0; j < 4; ++j) {
          const int lc = wo * 64 + j * 16 + (lane & 15);
          const float v = acc[i][j][r] + biasp[lc];
          const float vo = __shfl_xor(v, 1, 64);  // partner col value
          if (!(lane & 1)) {
            float r0 = v, r1 = vo;
            if (isK) {
              // rotate by alpha = w·mc[m] + b
              const float4 wj = rpe_l[(cb + lc) >> 1];
              const float ang = fmaf(wj.x, c0, fmaf(wj.y, c1, fmaf(wj.z, c2, wj.w)));
              float sn, cs; tsincos(ang, sn, cs);
              r0 = fmaf(v, cs, -(vo * sn));
              r1 = fmaf(v, sn, vo * cs);
            }
            const int pk = __builtin_amdgcn_cvt_pk_fp8_f32(r0, r1, 0, false);
            *(unsigned short*)(of8 + rowg * 256 + cb + lc) = (unsigned short)pk;
          }
        }
      }
    }
  }
}

// ---------- fused gather + MHA: pure dot-product scores (RoPE pre-applied) ----------
__global__ __launch_bounds__(256, 6) void attn5(
    const unsigned short* __restrict__ qb,   // N x 256 (bf16, beta-rotated)
    const unsigned char* __restrict__ kf8,   // M x 256 (fp8, alpha-rotated)
    const unsigned char* __restrict__ vf8,   // M x 256 (fp8)
    const int* __restrict__ idx,             // N x 32
    const float* __restrict__ mask,          // N x 32
    unsigned short* __restrict__ hb)         // N x 256 (bf16)
{
  __shared__ int idx_s[32];
  __shared__ float mask_s[32];
  __shared__ float p_s[256];
  __shared__ __attribute__((aligned(16))) unsigned char vls[32][256];

  const int n = blockIdx.x, t = threadIdx.x;
  if (t < 32) { idx_s[t] = idx[n * 32 + t]; mask_s[t] = mask[n * 32 + t]; }
  __syncthreads();

  // stage V fp8 (8KB) via global_load_lds, overlapped with score phase
#pragma unroll
  for (int i = 0; i < 2; ++i) {
    const int b = i * 4096 + t * 16;
    const int r = b >> 8, cb = b & 255;
    gload_lds16(vf8 + (long)idx_s[r] * 256 + cb, (char*)vls + b);
  }

  const int h = t >> 5, k = t & 31;
  const long krow = idx_s[k];

  uint4 kw[2];   // 32 fp8 bytes of K for this (k, head)
  {
    const uint4* kp = (const uint4*)(kf8 + krow * 256 + h * 32);
    kw[0] = kp[0]; kw[1] = kp[1];
  }
  u16x8 qv8[4];
  {
    const u16x8* qp = (const u16x8*)(qb + (long)n * 256 + h * 32);
#pragma unroll
    for (int i = 0; i < 4; ++i) qv8[i] = qp[i];
  }

  float sc = 0.f;
#pragma unroll
  for (int j2 = 0; j2 < 16; ++j2) {
    const unsigned dw = ((const unsigned*)kw)[j2 >> 1];
    const unsigned sh = (j2 & 1) * 16;
    const float x0 = fp8tof((dw >> sh) & 0xffu);
    const float x1 = fp8tof((dw >> (sh + 8)) & 0xffu);
    const int wi = j2 >> 2, e0 = (j2 & 3) * 2;
    sc = fmaf(bf2f(qv8[wi][e0]), x0, sc);
    sc = fmaf(bf2f(qv8[wi][e0 + 1]), x1, sc);
  }
  sc = sc * 0.17677669529663687f - 1e6f * (1.f - mask_s[k]);

  float mx = sc;
#pragma unroll
  for (int m = 16; m > 0; m >>= 1) mx = fmaxf(mx, __shfl_xor(mx, m, 32));
  const float e = __expf(sc - mx);
  float sum = e;
#pragma unroll
  for (int m = 16; m > 0; m >>= 1) sum += __shfl_xor(sum, m, 32);
  p_s[t] = e / sum;
  __syncthreads();  // V staged + p_s visible

  float acc = 0.f;
#pragma unroll
  for (int k4 = 0; k4 < 8; ++k4) {
    const float4 p4 = *(const float4*)(p_s + (t >> 5) * 32 + k4 * 4);
    acc = fmaf(p4.x, fp8tof(vls[k4 * 4 + 0][t]), acc);
    acc = fmaf(p4.y, fp8tof(vls[k4 * 4 + 1][t]), acc);
    acc = fmaf(p4.z, fp8tof(vls[k4 * 4 + 2][t]), acc);
    acc = fmaf(p4.w, fp8tof(vls[k4 * 4 + 3][t]), acc);
  }
  hb[(long)n * 256 + t] = f2bf(acc);
}

// ---------- bf16 GEMM + relu + bf16 out (FFN1). BM=64, BN=128 ----------
__global__ __launch_bounds__(256, 2) void gemm_relu(
    const unsigned short* __restrict__ A,   // M x 256
    const unsigned short* __restrict__ W,   // 512 x 256
    const float* __restrict__ bias,         // 512
    unsigned short* __restrict__ outb) {    // M x 512
  __shared__ __attribute__((aligned(16))) char lds[(64 + 128) * 64];
  const int tid = threadIdx.x, lane = tid & 63;
  const int wm = tid >> 7, wo = (tid >> 6) & 1;
  const long bm = blockIdx.x, bo = blockIdx.y;

  f32x4 acc[2][4] = {};
  const char* Ab = (const char*)(A + bm * 64 * 256);
  const char* Wb = (const char*)(W + bo * 128 * 256);
  for (int kt = 0; kt < 8; ++kt) {
    {
      const int fb = tid * 16;
      gload_lds16(Ab + (long)(fb >> 6) * 512 + kt * 64 + (fb & 63), lds + fb);
    }
#pragma unroll
    for (int c = 0; c < 2; ++c) {
      const int fb = c * 4096 + tid * 16;
      gload_lds16(Wb + (long)(fb >> 6) * 512 + kt * 64 + (fb & 63), lds + 4096 + fb);
    }
    __syncthreads();
    bf16x8 af[2], bfr[4];
    const int kb = (lane >> 4) * 16;
#pragma unroll
    for (int i = 0; i < 2; ++i)
      af[i] = *(const bf16x8*)(lds + (wm * 32 + i * 16 + (lane & 15)) * 64 + kb);
#pragma unroll
    for (int j = 0; j < 4; ++j)
      bfr[j] = *(const bf16x8*)(lds + 4096 + (wo * 64 + j * 16 + (lane & 15)) * 64 + kb);
#pragma unroll
    for (int i = 0; i < 2; ++i)
#pragma unroll
      for (int j = 0; j < 4; ++j)
        acc[i][j] = __builtin_amdgcn_mfma_f32_16x16x32_bf16(af[i], bfr[j], acc[i][j], 0, 0, 0);
    __syncthreads();
  }
#pragma unroll
  for (int i = 0; i < 2; ++i) {
#pragma unroll
    for (int j = 0; j < 4; ++j) {
      const int colg = (int)bo * 128 + wo * 64 + j * 16 + (lane & 15);
      const float bvv = bias[colg];
#pragma unroll
      for (int r = 0; r < 4; ++r) {
        const long rowg = bm * 64 + wm * 32 + i * 16 + (lane >> 4) * 4 + r;
        const float v = acc[i][j][r] + bvv;
        outb[rowg * 512 + colg] = f2bf(v > 0.f ? v : 0.f);
      }
    }
  }
}

// ---------- GEMM + bias + residual + LayerNorm fused epilogue ----------
// BM=16, BN=256 (full row per block), grid (M/16). KT = K/32.
template <int KT, int OUT_BF16, int RES_BF16>
__global__ __launch_bounds__(256, 2) void gemm_ln(
    const unsigned short* __restrict__ A,   // M x K bf16
    const unsigned short* __restrict__ W,   // 256 x K bf16
    const float* __restrict__ bias,         // 256
    const float* __restrict__ resf,         // M x 256 f32 (RES_BF16=0)
    const unsigned short* __restrict__ resb,// M x 256 bf16 (RES_BF16=1)
    const float* __restrict__ g, const float* __restrict__ b,
    float* __restrict__ outf,
    unsigned short* __restrict__ outb) {
  __shared__ __attribute__((aligned(16))) char lds[1024 + 16384];  // A 1KB | B 16KB
  __shared__ float2 part[4][16];
  const int tid = threadIdx.x, lane = tid & 63;
  const int wo = tid >> 6;
  const long bm = blockIdx.x;
  constexpr int K = KT * 32;

  f32x4 acc[4] = {};
  const char* Ab = (const char*)(A + bm * 16 * (long)K);
  for (int kt = 0; kt < KT; ++kt) {
    if (tid < 64) {
      const int fb = tid * 16;
      gload_lds16(Ab + (long)(fb >> 6) * (K * 2) + kt * 64 + (fb & 63), lds + fb);
    }
#pragma unroll
    for (int c = 0; c < 4; ++c) {
      const int fb = c * 4096 + tid * 16;
      gload_lds16((const char*)W + (long)(fb >> 6) * (K * 2) + kt * 64 + (fb & 63), lds + 1024 + fb);
    }
    __syncthreads();
    bf16x8 af, bfr[4];
    const int kb = (lane >> 4) * 16;
    af = *(const bf16x8*)(lds + ((lane & 15)) * 64 + kb);
#pragma unroll
    for (int j = 0; j < 4; ++j)
      bfr[j] = *(const bf16x8*)(lds + 1024 + (wo * 64 + j * 16 + (lane & 15)) * 64 + kb);
#pragma unroll
    for (int j = 0; j < 4; ++j)
      acc[j] = __builtin_amdgcn_mfma_f32_16x16x32_bf16(af, bfr[j], acc[j], 0, 0, 0);
    __syncthreads();
  }

  float gj[4], bj[4], biasj[4];
  int colg[4];
#pragma unroll
  for (int j = 0; j < 4; ++j) {
    colg[j] = wo * 64 + j * 16 + (lane & 15);
    gj[j] = g[colg[j]]; bj[j] = b[colg[j]]; biasj[j] = bias[colg[j]];
  }
  float v[4][4];
#pragma unroll
  for (int r = 0; r < 4; ++r) {
    const int row_local = (lane >> 4) * 4 + r;
    const long rowg = bm * 16 + row_local;
    float s = 0.f, s2 = 0.f;
#pragma unroll
    for (int j = 0; j < 4; ++j) {
      const float rv = RES_BF16 ? bf2f(resb[rowg * 256 + colg[j]]) : resf[rowg * 256 + colg[j]];
      float vv = acc[j][r] + biasj[j] + rv;
      v[j][r] = vv;
      s += vv; s2 = fmaf(vv, vv, s2);
    }
#pragma unroll
    for (int m = 8; m > 0; m >>= 1) { s += __shfl_xor(s, m, 16); s2 += __shfl_xor(s2, m, 16); }
    if ((lane & 15) == 0) part[wo][row_local] = make_float2(s, s2);
  }
  __syncthreads();
#pragma unroll
  for (int r = 0; r < 4; ++r) {
    const int row_local = (lane >> 4) * 4 + r;
    const long rowg = bm * 16 + row_local;
    float s = 0.f, s2 = 0.f;
#pragma unroll
    for (int wq = 0; wq < 4; ++wq) { s += part[wq][row_local].x; s2 += part[wq][row_local].y; }
    const float mu = s * (1.f / 256.f);
    const float var = s2 * (1.f / 256.f) - mu * mu;
    const float inv = rsqrtf(var + 1e-5f);
#pragma unroll
    for (int j = 0; j < 4; ++j) {
      const float y = (v[j][r] - mu) * inv * gj[j] + bj[j];
      if (OUT_BF16) outb[rowg * 256 + colg[j]] = f2bf(y);
      else outf[rowg * 256 + colg[j]] = y;
    }
  }
}

// ---------- launch ----------
extern "C" void kernel_launch(void* const* d_in, const int* in_sizes, int n_in,
                              void* d_out, int out_size, void* d_ws, size_t ws_size,
                              hipStream_t stream) {
  const float* x    = (const float*)d_in[0];
  const float* mem  = (const float*)d_in[1];
  const int* idx    = (const int*)d_in[2];
  const float* ic   = (const float*)d_in[3];
  const float* mc   = (const float*)d_in[4];
  const float* mask = (const float*)d_in[5];
  const float* Wq = (const float*)d_in[6];  const float* bq = (const float*)d_in[7];
  const float* Wk = (const float*)d_in[8];  const float* bk = (const float*)d_in[9];
  const float* Wv = (const float*)d_in[10]; const float* bv = (const float*)d_in[11];
  const float* Wo = (const float*)d_in[12]; const float* bo = (const float*)d_in[13];
  const float* g1 = (const float*)d_in[14]; const float* b1 = (const float*)d_in[15];
  const float* Wrpe = (const float*)d_in[16]; const float* brpe = (const float*)d_in[17];
  const float* We = (const float*)d_in[18]; const float* be = (const float*)d_in[19];
  const float* Ws = (const float*)d_in[20]; const float* bs = (const float*)d_in[21];
  const float* g2 = (const float*)d_in[22]; const float* b2 = (const float*)d_in[23];

  char* w = (char*)d_ws;
  const size_t MB = 1ull << 20;
  unsigned char*  kf8   = (unsigned char*)(w + 0);         // 2MB (M x 256 fp8)
  unsigned char*  vf8   = (unsigned char*)(w + 2 * MB);    // 2MB
  unsigned short* qbuf  = (unsigned short*)(w + 4 * MB);   // 4MB
  unsigned short* hb    = (unsigned short*)(w + 8 * MB);   // 4MB
  unsigned short* out1b = (unsigned short*)(w + 12 * MB);  // 4MB
  unsigned short* ffb   = (unsigned short*)(w + 16 * MB);  // 8MB (8192x512 bf16)
  unsigned short* wob  = (unsigned short*)(w + 24 * MB);   // 128KB
  unsigned short* web  = wob + 65536;                      // 256KB
  unsigned short* wsb  = web + 131072;                     // 256KB

  // fused q/k/v projections (+ absolute RoPE) + weight conversions (one launch)
  gemm_proj<<<dim3(128, 7), 256, 0, stream>>>(
      x, mem, Wq, Wk, Wv, Wo, We, Ws, Wrpe, brpe, bq, bk, bv, ic, mc,
      qbuf, kf8, vf8, wob, web, wsb);

  // fused gather + attention (pure dot-product scores)
  attn5<<<8192, 256, 0, stream>>>(qbuf, kf8, vf8, idx, mask, hb);

  // output proj + residual(x, f32) + LN1 -> bf16
  gemm_ln<8, 1, 0><<<512, 256, 0, stream>>>(
      hb, wob, bo, x, nullptr, g1, b1, nullptr, out1b);

  // FFN1 (relu)
  gemm_relu<<<dim3(128, 4), 256, 0, stream>>>(out1b, web, be, ffb);

  // FFN2 + residual(out1b, bf16) + LN2 -> d_out (f32)
  gemm_ln<16, 0, 1><<<512, 256, 0, stream>>>(
      ffb, wsb, bs, nullptr, out1b, g2, b2, (float*)d_out, nullptr);
}